// Round 3
// baseline (2078.821 us; speedup 1.0000x reference)
//
#include <hip/hip_runtime.h>
#include <math.h>
#include <float.h>

#define NB 8
#define NC 24
#define NA 96
#define NW 96
#define NF 32
#define NHID 128
#define AW (NA*NW)           // 9216
#define NBC (NB*NC)          // 192
#define NEL ((size_t)NBC*AW) // 1769472

// ---------------------------------------------------------------- stats
__global__ __launch_bounds__(256) void stats_kernel(
    const float* __restrict__ x, const int* __restrict__ rows_len,
    const int* __restrict__ cols_len, float* __restrict__ stats)
{
    int bc = blockIdx.x;
    int R = rows_len[bc], L = cols_len[bc];
    const float* xp = x + (size_t)bc * AW;
    int n = R * L;
    float sx = 0.f, sxx = 0.f;
    for (int i = threadIdx.x; i < n; i += 256) {
        int a = i / L, w = i - a * L;
        float v = xp[a * NW + w];
        sx += v;
        sxx = fmaf(v, v, sxx);
    }
    __shared__ float r1[256], r2[256];
    r1[threadIdx.x] = sx; r2[threadIdx.x] = sxx;
    __syncthreads();
    for (int s = 128; s > 0; s >>= 1) {
        if (threadIdx.x < s) {
            r1[threadIdx.x] += r1[threadIdx.x + s];
            r2[threadIdx.x] += r2[threadIdx.x + s];
        }
        __syncthreads();
    }
    if (threadIdx.x == 0) {
        float fn = (float)n;
        float mean = r1[0] / fn;
        float var = fmaxf((r2[0] - r1[0] * r1[0] / fn) / (fn - 1.f), 0.f);
        float sd = fmaxf(sqrtf(var), 1e-12f);
        stats[2 * bc] = mean;
        stats[2 * bc + 1] = 1.f / sd;
    }
}

// ---------------------------------------------------------------- prep: transpose first 24 rows of each stack's W1
__global__ __launch_bounds__(256) void prep_kernel(
    const float* __restrict__ tw1, float* __restrict__ w1t)
{
    int i = blockIdx.x * 256 + threadIdx.x;     // [s][j][t]
    if (i >= 4 * NHID * 24) return;
    int s = i / (NHID * 24), r = i % (NHID * 24);
    int j = r / 24, t = r % 24;
    w1t[i] = tw1[(size_t)s * 64 * NHID + t * NHID + j];
}

// ---------------------------------------------------------------- t0 MLP (1->128->32), writes planar h
__global__ __launch_bounds__(256) void t0_kernel(
    const float* __restrict__ x, const int* __restrict__ rows_len,
    const int* __restrict__ cols_len, const float* __restrict__ stats,
    const float* __restrict__ w1, const float* __restrict__ b1,
    const float* __restrict__ w2, const float* __restrict__ b2,
    float* __restrict__ h)
{
    int tid = threadIdx.x;
    int bc = blockIdx.x / 18;
    int base = (blockIdx.x % 18) * 512;
    int R = rows_len[bc], L = cols_len[bc];
    float mean = stats[2 * bc], rstd = stats[2 * bc + 1];

    int eA = base + tid, eB = eA + 256;
    int aA = eA / NW, wA = eA % NW;
    int aB = eB / NW, wB = eB % NW;
    bool vA = (aA < R) && (wA < L);
    bool vB = (aB < R) && (wB < L);
    size_t gA = (size_t)bc * AW + eA;
    float xA = vA ? (x[gA] - mean) * rstd : 0.f;
    float xB = vB ? (x[gA + 256] - mean) * rstd : 0.f;

    float oA[NF], oB[NF];
    #pragma unroll
    for (int f = 0; f < NF; f++) { float bb = b2[f]; oA[f] = bb; oB[f] = bb; }
    for (int j = 0; j < NHID; j++) {
        float hA = fmaxf(fmaf(xA, w1[j], b1[j]), 0.f);
        float hB = fmaxf(fmaf(xB, w1[j], b1[j]), 0.f);
        const float* wr = &w2[j * NF];
        #pragma unroll
        for (int f = 0; f < NF; f++) {
            float q = wr[f];
            oA[f] = fmaf(hA, q, oA[f]);
            oB[f] = fmaf(hB, q, oB[f]);
        }
    }
    float mA = vA ? 1.f : 0.f, mB = vB ? 1.f : 0.f;
    float* hp = h + (size_t)bc * NF * AW;
    #pragma unroll
    for (int f = 0; f < NF; f++) {
        hp[(size_t)f * AW + eA] = oA[f] * mA;
        hp[(size_t)f * AW + eB] = oB[f] * mB;
    }
}

// ---------------------------------------------------------------- pools: one block per (bc, f) plane
__global__ __launch_bounds__(256) void pool_kernel(
    const float* __restrict__ h, float* __restrict__ rowsum,
    float* __restrict__ colsum, float* __restrict__ matsum,
    float* __restrict__ cmax)
{
    __shared__ float sred[4];
    __shared__ float scol[4][96];
    int blk = blockIdx.x;            // bc*32 + f
    int bc = blk >> 5, f = blk & 31;
    const float* p = h + (size_t)blk * AW;
    int tid = threadIdx.x;
    int lane = tid & 63, wv = tid >> 6;

    // ---- max over plane (coalesced strided pass)
    float mx = -FLT_MAX;
    for (int i = tid; i < AW; i += 256) mx = fmaxf(mx, p[i]);
    #pragma unroll
    for (int off = 32; off >= 1; off >>= 1) mx = fmaxf(mx, __shfl_xor(mx, off, 64));
    if (lane == 0) sred[wv] = mx;
    __syncthreads();
    if (tid == 0)
        cmax[bc * NF + f] = fmaxf(fmaxf(sred[0], sred[1]), fmaxf(sred[2], sred[3]));

    int mode = f & 3, k = f >> 2;
    if (mode == 1) {
        // row sums of sin: wave per row (rows wv, wv+4, ...)
        for (int r = 0; r < 24; r++) {
            int a = wv + 4 * r;
            float v1 = p[a * NW + lane];
            float s = sinf(v1);
            if (lane < 32) s += sinf(p[a * NW + 64 + lane]);
            #pragma unroll
            for (int off = 32; off >= 1; off >>= 1) s += __shfl_xor(s, off, 64);
            if (lane == 0) rowsum[(bc * NA + a) * 8 + k] = s;
        }
    } else if (mode == 2) {
        // col sums of sin: lane l accumulates col l (and 64+l for l<32)
        float acc0 = 0.f, acc1 = 0.f;
        for (int r = 0; r < 24; r++) {
            int a = wv + 4 * r;
            acc0 += sinf(p[a * NW + lane]);
            if (lane < 32) acc1 += sinf(p[a * NW + 64 + lane]);
        }
        scol[wv][lane] = acc0;
        if (lane < 32) scol[wv][64 + lane] = acc1;
        __syncthreads();
        if (tid < 96)
            colsum[(bc * NW + tid) * 8 + k] =
                scol[0][tid] + scol[1][tid] + scol[2][tid] + scol[3][tid];
    } else if (mode == 3) {
        // matrix sum of sin
        float s = 0.f;
        for (int i = tid; i < AW; i += 256) s += sinf(p[i]);
        #pragma unroll
        for (int off = 32; off >= 1; off >>= 1) s += __shfl_xor(s, off, 64);
        __syncthreads();
        if (lane == 0) sred[wv] = s;
        __syncthreads();
        if (tid == 0) matsum[bc * 8 + k] = sred[0] + sred[1] + sred[2] + sred[3];
    }
}

// ---------------------------------------------------------------- precompute per-(bc): rowc[j][a], colc[j][w]
// rowc = b1 + matsum-term + batchmax-term + rowsum-term (everything that only
// depends on (bc,a,j));  colc = colsum-term only (depends on (bc,w,j)).
__global__ __launch_bounds__(256) void precomp_kernel(
    const float* __restrict__ rowsum, const float* __restrict__ colsum,
    const float* __restrict__ matsum, const float* __restrict__ cmax,
    const float* __restrict__ w1, const float* __restrict__ b1,
    float* __restrict__ rowc, float* __restrict__ colc)
{
    __shared__ float sbm[NF];
    __shared__ float sconst[NHID];
    int tid = threadIdx.x;
    int bc = blockIdx.x, b = bc / NC;
    if (tid < NF) {
        float m = cmax[(b * NC) * NF + tid];
        for (int c = 1; c < NC; c++) m = fmaxf(m, cmax[(b * NC + c) * NF + tid]);
        sbm[tid] = m;
    }
    __syncthreads();
    if (tid < NHID) {
        float v = b1[tid];
        const float* mp = matsum + bc * 8;
        #pragma unroll
        for (int k = 0; k < 8; k++) v = fmaf(mp[k], w1[(24 + k) * NHID + tid], v);
        #pragma unroll
        for (int f = 0; f < NF; f++) v = fmaf(sbm[f], w1[(32 + f) * NHID + tid], v);
        sconst[tid] = v;
    }
    __syncthreads();
    for (int i = tid; i < NHID * NA; i += 256) {
        int j = i / NA, aa = i - j * NA;
        const float* rp = rowsum + (bc * NA + aa) * 8;
        float v = sconst[j];
        #pragma unroll
        for (int k = 0; k < 8; k++) v = fmaf(rp[k], w1[(8 + k) * NHID + j], v);
        rowc[(size_t)bc * (NHID * NA) + i] = v;
    }
    for (int i = tid; i < NHID * NW; i += 256) {
        int j = i / NW, ww = i - j * NW;
        const float* cp = colsum + (bc * NW + ww) * 8;
        float v = 0.f;
        #pragma unroll
        for (int k = 0; k < 8; k++) v = fmaf(cp[k], w1[(16 + k) * NHID + j], v);
        colc[(size_t)bc * (NHID * NW) + i] = v;
    }
}

// ---------------------------------------------------------------- stack MLP v5: j-blocked + VGPR pins
// Round-2 lesson: with VGPR cap 40 the compiler SPILLED v[8] (VALUBusy 85->65).
// Fix: (a) __launch_bounds__(512,4) -> 128-VGPR budget; (b) zero-cost asm pins
// force v[8] and all o[32] to live in VGPRs each j0 block, making f-loop
// distribution (the remat split) illegal. Accumulation order unchanged.
__global__ __launch_bounds__(512, 4) void mlp_kernel(
    float* __restrict__ h, const float* __restrict__ rowc,
    const float* __restrict__ colc, const int* __restrict__ rows_len,
    const int* __restrict__ cols_len, const float* __restrict__ w1t,
    const float* __restrict__ w2, const float* __restrict__ b2)
{
    __shared__ float scol[NHID * NW];   // [j][w]  48 KB, conflict-free reads
    __shared__ float srow[NHID * 8];    // [j][da]  4 KB, broadcast reads
    int tid = threadIdx.x;
    int bc = blockIdx.x / 18;
    int base = (blockIdx.x % 18) * 512;
    int a0 = base / NW;                 // block spans rows a0..a0+5

    const float* cg = colc + (size_t)bc * (NHID * NW);
    for (int i = tid; i < NHID * NW; i += 512) scol[i] = cg[i];
    const float* rg = rowc + (size_t)bc * (NHID * NA);
    for (int i = tid; i < NHID * 8; i += 512) {
        int j = i >> 3, da = i & 7, a = a0 + da;
        srow[i] = (a < NA) ? rg[j * NA + a] : 0.f;
    }
    __syncthreads();

    int R = rows_len[bc], L = cols_len[bc];
    int e = base + tid;
    int a = e / NW, w = e % NW;
    int da = a - a0;
    float mk = (a < R && w < L) ? 1.f : 0.f;

    float* hp = h + (size_t)bc * NF * AW;
    float p[8];
    #pragma unroll
    for (int k = 0; k < 8; k++) p[k] = sinf(hp[(size_t)(4 * k) * AW + e]);

    float o[NF];
    #pragma unroll
    for (int f = 0; f < NF; f++) o[f] = b2[f];

    for (int j0 = 0; j0 < NHID; j0 += 8) {
        float v[8];
        #pragma unroll
        for (int jj = 0; jj < 8; jj++) {
            int j = j0 + jj;
            const float* w1r = w1t + j * 24;      // uniform -> s_load
            // two independent 4-FMA chains (same order as before -> same rounding)
            float u1 = srow[j * 8 + da];
            float u2 = scol[j * NW + w];
            #pragma unroll
            for (int k = 0; k < 8; k += 2) {
                u1 = fmaf(p[k],     w1r[k],     u1);
                u2 = fmaf(p[k + 1], w1r[k + 1], u2);
            }
            v[jj] = fmaxf(u1 + u2, 0.f);
        }
        // pin hidden values in VGPRs: spilling/rematting them is now impossible
        asm volatile("" : "+v"(v[0]), "+v"(v[1]), "+v"(v[2]), "+v"(v[3]),
                          "+v"(v[4]), "+v"(v[5]), "+v"(v[6]), "+v"(v[7]));
        #pragma unroll
        for (int jj = 0; jj < 8; jj++) {
            const float* w2r = w2 + (j0 + jj) * NF;   // uniform -> s_load
            float vv = v[jj];
            #pragma unroll
            for (int f = 0; f < NF; f++) o[f] = fmaf(vv, w2r[f], o[f]);
        }
        // pin all 32 accumulators: every j0 iteration touches all o[f], so the
        // compiler cannot distribute the f-loop across the j-loop (the remat
        // split that cost 1.55x VALU in r1 and scratch spills in r2).
        asm volatile("" : "+v"(o[0]),  "+v"(o[1]),  "+v"(o[2]),  "+v"(o[3]),
                          "+v"(o[4]),  "+v"(o[5]),  "+v"(o[6]),  "+v"(o[7]),
                          "+v"(o[8]),  "+v"(o[9]),  "+v"(o[10]), "+v"(o[11]),
                          "+v"(o[12]), "+v"(o[13]), "+v"(o[14]), "+v"(o[15]));
        asm volatile("" : "+v"(o[16]), "+v"(o[17]), "+v"(o[18]), "+v"(o[19]),
                          "+v"(o[20]), "+v"(o[21]), "+v"(o[22]), "+v"(o[23]),
                          "+v"(o[24]), "+v"(o[25]), "+v"(o[26]), "+v"(o[27]),
                          "+v"(o[28]), "+v"(o[29]), "+v"(o[30]), "+v"(o[31]));
    }
    #pragma unroll
    for (int f = 0; f < NF; f++) {                // residual read-modify-write
        float* addr = hp + (size_t)f * AW + e;
        *addr = (*addr + o[f]) * mk;
    }
}

// ---------------------------------------------------------------- RMS over (a,w)
__global__ __launch_bounds__(256) void rms_kernel(
    const float* __restrict__ h, const int* __restrict__ rows_len,
    const int* __restrict__ cols_len, float* __restrict__ rms)
{
    int bc = blockIdx.x;
    int f = threadIdx.x >> 3, g = threadIdx.x & 7;
    const float* p = h + ((size_t)bc * NF + f) * AW;
    float s = 0.f;
    for (int i = g; i < AW; i += 8) { float v = p[i]; s = fmaf(v, v, s); }
    __shared__ float red[NF][9];
    red[f][g] = s;
    __syncthreads();
    if (threadIdx.x < NF) {
        float t = 0.f;
        #pragma unroll
        for (int g2 = 0; g2 < 8; g2++) t += red[threadIdx.x][g2];
        float n = (float)(rows_len[bc] * cols_len[bc]);
        t = fmaxf(t, 1e-20f);
        rms[bc * NF + threadIdx.x] = sqrtf(t / fmaxf(n, 1e-12f));
    }
}

// ---------------------------------------------------------------- final mean-over-C + MLP + tanh
__global__ __launch_bounds__(64) void out_kernel(
    const float* __restrict__ rms, const float* __restrict__ w1,
    const float* __restrict__ b1, const float* __restrict__ w2,
    const float* __restrict__ b2, float* __restrict__ out)
{
    int b = threadIdx.x;
    if (b >= NB) return;
    float hm[NF];
    #pragma unroll
    for (int f = 0; f < NF; f++) {
        float s = 0.f;
        for (int c = 0; c < NC; c++) s += rms[(b * NC + c) * NF + f];
        hm[f] = s / (float)NC;
    }
    float o0 = b2[0], o1 = b2[1];
    for (int j = 0; j < NHID; j++) {
        float v = b1[j];
        #pragma unroll
        for (int f = 0; f < NF; f++) v = fmaf(hm[f], w1[f * NHID + j], v);
        v = fmaxf(v, 0.f);
        o0 = fmaf(v, w2[j * 2 + 0], o0);
        o1 = fmaf(v, w2[j * 2 + 1], o1);
    }
    out[b * 2 + 0] = 8.f * tanhf(o0);
    out[b * 2 + 1] = 8.f * tanhf(o1);
}

// ---------------------------------------------------------------- launcher
extern "C" void kernel_launch(void* const* d_in, const int* in_sizes, int n_in,
                              void* d_out, int out_size, void* d_ws, size_t ws_size,
                              hipStream_t stream)
{
    const float* x    = (const float*)d_in[0];
    const int* rl     = (const int*)d_in[1];
    const int* cl     = (const int*)d_in[2];
    const float* t0w1 = (const float*)d_in[3];
    const float* t0b1 = (const float*)d_in[4];
    const float* t0w2 = (const float*)d_in[5];
    const float* t0b2 = (const float*)d_in[6];
    const float* tw1  = (const float*)d_in[7];
    const float* tb1  = (const float*)d_in[8];
    const float* tw2  = (const float*)d_in[9];
    const float* tb2  = (const float*)d_in[10];
    const float* ow1  = (const float*)d_in[11];
    const float* ob1  = (const float*)d_in[12];
    const float* ow2  = (const float*)d_in[13];
    const float* ob2  = (const float*)d_in[14];
    float* out = (float*)d_out;

    float* ws    = (float*)d_ws;
    float* h     = ws;                               // NEL*NF  (planar [bc][f][a*96+w])
    float* stats = h + NEL * NF;                     // 2*NBC
    float* rowb  = stats + 2 * NBC;                  // NBC*NA*8
    float* colb  = rowb + (size_t)NBC * NA * 8;      // NBC*NW*8
    float* matb  = colb + (size_t)NBC * NW * 8;      // NBC*8
    float* cmxb  = matb + NBC * 8;                   // NBC*NF
    float* rmsb  = cmxb + NBC * NF;                  // NBC*NF
    float* w1tb  = rmsb + NBC * NF;                  // 4*NHID*24
    float* rowcb = w1tb + 4 * NHID * 24;             // NBC*NHID*NA
    float* colcb = rowcb + (size_t)NBC * NHID * NA;  // NBC*NHID*NW

    stats_kernel<<<NBC, 256, 0, stream>>>(x, rl, cl, stats);
    prep_kernel<<<(4 * NHID * 24 + 255) / 256, 256, 0, stream>>>(tw1, w1tb);
    t0_kernel<<<(int)(NEL / 512), 256, 0, stream>>>(x, rl, cl, stats,
                                                    t0w1, t0b1, t0w2, t0b2, h);
    for (int s = 0; s < 4; s++) {
        pool_kernel<<<NBC * NF, 256, 0, stream>>>(h, rowb, colb, matb, cmxb);
        precomp_kernel<<<NBC, 256, 0, stream>>>(rowb, colb, matb, cmxb,
            tw1 + (size_t)s * 64 * NHID, tb1 + s * NHID, rowcb, colcb);
        mlp_kernel<<<NBC * 18, 512, 0, stream>>>(h, rowcb, colcb, rl, cl,
            w1tb + (size_t)s * NHID * 24,
            tw2 + (size_t)s * NHID * NF, tb2 + s * NF);
    }
    rms_kernel<<<NBC, 256, 0, stream>>>(h, rl, cl, rmsb);
    out_kernel<<<1, 64, 0, stream>>>(rmsb, ow1, ob1, ow2, ob2, out);
}

// Round 4
// 1732.890 us; speedup vs baseline: 1.1996x; 1.1996x over previous
//
#include <hip/hip_runtime.h>
#include <math.h>
#include <float.h>

#define NB 8
#define NC 24
#define NA 96
#define NW 96
#define NF 32
#define NHID 128
#define AW (NA*NW)           // 9216
#define NBC (NB*NC)          // 192
#define NEL ((size_t)NBC*AW) // 1769472

// packed fp32: <2 x float> fma -> v_pk_fma_f32 on gfx90a+/gfx950
typedef float v2f __attribute__((ext_vector_type(2)));
#ifndef __has_builtin
#define __has_builtin(x) 0
#endif
#if __has_builtin(__builtin_elementwise_fma)
#define PKFMA(a,b,c) __builtin_elementwise_fma((a),(b),(c))
#else
#define PKFMA(a,b,c) ((a)*(b)+(c))   // HIP default fp-contract fuses this
#endif

// ---------------------------------------------------------------- stats
__global__ __launch_bounds__(256) void stats_kernel(
    const float* __restrict__ x, const int* __restrict__ rows_len,
    const int* __restrict__ cols_len, float* __restrict__ stats)
{
    int bc = blockIdx.x;
    int R = rows_len[bc], L = cols_len[bc];
    const float* xp = x + (size_t)bc * AW;
    int n = R * L;
    float sx = 0.f, sxx = 0.f;
    for (int i = threadIdx.x; i < n; i += 256) {
        int a = i / L, w = i - a * L;
        float v = xp[a * NW + w];
        sx += v;
        sxx = fmaf(v, v, sxx);
    }
    __shared__ float r1[256], r2[256];
    r1[threadIdx.x] = sx; r2[threadIdx.x] = sxx;
    __syncthreads();
    for (int s = 128; s > 0; s >>= 1) {
        if (threadIdx.x < s) {
            r1[threadIdx.x] += r1[threadIdx.x + s];
            r2[threadIdx.x] += r2[threadIdx.x + s];
        }
        __syncthreads();
    }
    if (threadIdx.x == 0) {
        float fn = (float)n;
        float mean = r1[0] / fn;
        float var = fmaxf((r2[0] - r1[0] * r1[0] / fn) / (fn - 1.f), 0.f);
        float sd = fmaxf(sqrtf(var), 1e-12f);
        stats[2 * bc] = mean;
        stats[2 * bc + 1] = 1.f / sd;
    }
}

// ---------------------------------------------------------------- prep: transpose first 24 rows of each stack's W1
__global__ __launch_bounds__(256) void prep_kernel(
    const float* __restrict__ tw1, float* __restrict__ w1t)
{
    int i = blockIdx.x * 256 + threadIdx.x;     // [s][j][t]
    if (i >= 4 * NHID * 24) return;
    int s = i / (NHID * 24), r = i % (NHID * 24);
    int j = r / 24, t = r % 24;
    w1t[i] = tw1[(size_t)s * 64 * NHID + t * NHID + j];
}

// ---------------------------------------------------------------- t0 MLP (1->128->32), packed-f accumulation
__global__ __launch_bounds__(256) void t0_kernel(
    const float* __restrict__ x, const int* __restrict__ rows_len,
    const int* __restrict__ cols_len, const float* __restrict__ stats,
    const float* __restrict__ w1, const float* __restrict__ b1,
    const float* __restrict__ w2, const float* __restrict__ b2,
    float* __restrict__ h)
{
    int tid = threadIdx.x;
    int bc = blockIdx.x / 18;
    int base = (blockIdx.x % 18) * 512;
    int R = rows_len[bc], L = cols_len[bc];
    float mean = stats[2 * bc], rstd = stats[2 * bc + 1];

    int eA = base + tid, eB = eA + 256;
    int aA = eA / NW, wA = eA % NW;
    int aB = eB / NW, wB = eB % NW;
    bool vA = (aA < R) && (wA < L);
    bool vB = (aB < R) && (wB < L);
    size_t gA = (size_t)bc * AW + eA;
    float xA = vA ? (x[gA] - mean) * rstd : 0.f;
    float xB = vB ? (x[gA + 256] - mean) * rstd : 0.f;

    v2f oA[16], oB[16];
    const v2f* b22 = (const v2f*)b2;
    #pragma unroll
    for (int i = 0; i < 16; i++) { v2f bb = b22[i]; oA[i] = bb; oB[i] = bb; }
    for (int j = 0; j < NHID; j++) {
        float hA = fmaxf(fmaf(xA, w1[j], b1[j]), 0.f);
        float hB = fmaxf(fmaf(xB, w1[j], b1[j]), 0.f);
        const v2f* wr = (const v2f*)&w2[j * NF];
        v2f hA2 = {hA, hA}, hB2 = {hB, hB};
        #pragma unroll
        for (int i = 0; i < 16; i++) {
            v2f q = wr[i];
            oA[i] = PKFMA(hA2, q, oA[i]);
            oB[i] = PKFMA(hB2, q, oB[i]);
        }
    }
    float mA = vA ? 1.f : 0.f, mB = vB ? 1.f : 0.f;
    float* hp = h + (size_t)bc * NF * AW;
    #pragma unroll
    for (int f = 0; f < NF; f++) {
        hp[(size_t)f * AW + eA] = oA[f >> 1][f & 1] * mA;
        hp[(size_t)f * AW + eB] = oB[f >> 1][f & 1] * mB;
    }
}

// ---------------------------------------------------------------- pools: one block per (bc, f) plane
__global__ __launch_bounds__(256) void pool_kernel(
    const float* __restrict__ h, float* __restrict__ rowsum,
    float* __restrict__ colsum, float* __restrict__ matsum,
    float* __restrict__ cmax)
{
    __shared__ float sred[4];
    __shared__ float scol[4][96];
    int blk = blockIdx.x;            // bc*32 + f
    int bc = blk >> 5, f = blk & 31;
    const float* p = h + (size_t)blk * AW;
    int tid = threadIdx.x;
    int lane = tid & 63, wv = tid >> 6;

    // ---- max over plane (coalesced strided pass)
    float mx = -FLT_MAX;
    for (int i = tid; i < AW; i += 256) mx = fmaxf(mx, p[i]);
    #pragma unroll
    for (int off = 32; off >= 1; off >>= 1) mx = fmaxf(mx, __shfl_xor(mx, off, 64));
    if (lane == 0) sred[wv] = mx;
    __syncthreads();
    if (tid == 0)
        cmax[bc * NF + f] = fmaxf(fmaxf(sred[0], sred[1]), fmaxf(sred[2], sred[3]));

    int mode = f & 3, k = f >> 2;
    if (mode == 1) {
        // row sums of sin: wave per row (rows wv, wv+4, ...)
        for (int r = 0; r < 24; r++) {
            int a = wv + 4 * r;
            float v1 = p[a * NW + lane];
            float s = sinf(v1);
            if (lane < 32) s += sinf(p[a * NW + 64 + lane]);
            #pragma unroll
            for (int off = 32; off >= 1; off >>= 1) s += __shfl_xor(s, off, 64);
            if (lane == 0) rowsum[(bc * NA + a) * 8 + k] = s;
        }
    } else if (mode == 2) {
        // col sums of sin: lane l accumulates col l (and 64+l for l<32)
        float acc0 = 0.f, acc1 = 0.f;
        for (int r = 0; r < 24; r++) {
            int a = wv + 4 * r;
            acc0 += sinf(p[a * NW + lane]);
            if (lane < 32) acc1 += sinf(p[a * NW + 64 + lane]);
        }
        scol[wv][lane] = acc0;
        if (lane < 32) scol[wv][64 + lane] = acc1;
        __syncthreads();
        if (tid < 96)
            colsum[(bc * NW + tid) * 8 + k] =
                scol[0][tid] + scol[1][tid] + scol[2][tid] + scol[3][tid];
    } else if (mode == 3) {
        // matrix sum of sin
        float s = 0.f;
        for (int i = tid; i < AW; i += 256) s += sinf(p[i]);
        #pragma unroll
        for (int off = 32; off >= 1; off >>= 1) s += __shfl_xor(s, off, 64);
        __syncthreads();
        if (lane == 0) sred[wv] = s;
        __syncthreads();
        if (tid == 0) matsum[bc * 8 + k] = sred[0] + sred[1] + sred[2] + sred[3];
    }
}

// ---------------------------------------------------------------- precompute per-(bc): rowc[j][a], colc[j][w]
__global__ __launch_bounds__(256) void precomp_kernel(
    const float* __restrict__ rowsum, const float* __restrict__ colsum,
    const float* __restrict__ matsum, const float* __restrict__ cmax,
    const float* __restrict__ w1, const float* __restrict__ b1,
    float* __restrict__ rowc, float* __restrict__ colc)
{
    __shared__ float sbm[NF];
    __shared__ float sconst[NHID];
    int tid = threadIdx.x;
    int bc = blockIdx.x, b = bc / NC;
    if (tid < NF) {
        float m = cmax[(b * NC) * NF + tid];
        for (int c = 1; c < NC; c++) m = fmaxf(m, cmax[(b * NC + c) * NF + tid]);
        sbm[tid] = m;
    }
    __syncthreads();
    if (tid < NHID) {
        float v = b1[tid];
        const float* mp = matsum + bc * 8;
        #pragma unroll
        for (int k = 0; k < 8; k++) v = fmaf(mp[k], w1[(24 + k) * NHID + tid], v);
        #pragma unroll
        for (int f = 0; f < NF; f++) v = fmaf(sbm[f], w1[(32 + f) * NHID + tid], v);
        sconst[tid] = v;
    }
    __syncthreads();
    for (int i = tid; i < NHID * NA; i += 256) {
        int j = i / NA, aa = i - j * NA;
        const float* rp = rowsum + (bc * NA + aa) * 8;
        float v = sconst[j];
        #pragma unroll
        for (int k = 0; k < 8; k++) v = fmaf(rp[k], w1[(8 + k) * NHID + j], v);
        rowc[(size_t)bc * (NHID * NA) + i] = v;
    }
    for (int i = tid; i < NHID * NW; i += 256) {
        int j = i / NW, ww = i - j * NW;
        const float* cp = colsum + (bc * NW + ww) * 8;
        float v = 0.f;
        #pragma unroll
        for (int k = 0; k < 8; k++) v = fmaf(cp[k], w1[(16 + k) * NHID + j], v);
        colc[(size_t)bc * (NHID * NW) + i] = v;
    }
}

// ---------------------------------------------------------------- stack MLP v6: r1 structure + packed fp32
// Exact r1 (best measured: 244us) loop structure; the two hidden chains become
// one v_pk_fma_f32 chain (u.x = even-k seeded srow, u.y = odd-k seeded scol —
// identical pairing/rounding to r1), and the 32 f-accumulators become 16
// packed FMAs per j. Halves the dominant instruction streams; whatever remat
// schedule the compiler picks, its chunks halve too.
__global__ __launch_bounds__(512) void mlp_kernel(
    float* __restrict__ h, const float* __restrict__ rowc,
    const float* __restrict__ colc, const int* __restrict__ rows_len,
    const int* __restrict__ cols_len, const float* __restrict__ w1t,
    const float* __restrict__ w2, const float* __restrict__ b2)
{
    __shared__ float scol[NHID * NW];   // [j][w]  48 KB, conflict-free reads
    __shared__ float srow[NHID * 8];    // [j][da]  4 KB, broadcast reads
    int tid = threadIdx.x;
    int bc = blockIdx.x / 18;
    int base = (blockIdx.x % 18) * 512;
    int a0 = base / NW;                 // block spans rows a0..a0+5

    const float* cg = colc + (size_t)bc * (NHID * NW);
    for (int i = tid; i < NHID * NW; i += 512) scol[i] = cg[i];
    const float* rg = rowc + (size_t)bc * (NHID * NA);
    for (int i = tid; i < NHID * 8; i += 512) {
        int j = i >> 3, da = i & 7, a = a0 + da;
        srow[i] = (a < NA) ? rg[j * NA + a] : 0.f;
    }
    __syncthreads();

    int R = rows_len[bc], L = cols_len[bc];
    int e = base + tid;
    int a = e / NW, w = e % NW;
    int da = a - a0;
    float mk = (a < R && w < L) ? 1.f : 0.f;

    float* hp = h + (size_t)bc * NF * AW;
    float p[8];
    #pragma unroll
    for (int k = 0; k < 8; k++) p[k] = sinf(hp[(size_t)(4 * k) * AW + e]);
    v2f p2[4];
    #pragma unroll
    for (int t = 0; t < 4; t++) p2[t] = (v2f){p[2 * t], p[2 * t + 1]};

    v2f o[16];
    const v2f* b22 = (const v2f*)b2;
    #pragma unroll
    for (int i = 0; i < 16; i++) o[i] = b22[i];

    for (int j = 0; j < NHID; j++) {
        const v2f* w1r = (const v2f*)(w1t + j * 24);  // uniform -> s_load
        v2f u = {srow[j * 8 + da], scol[j * NW + w]};
        #pragma unroll
        for (int t = 0; t < 4; t++) u = PKFMA(p2[t], w1r[t], u);
        float v = fmaxf(u.x + u.y, 0.f);
        const v2f* w2r = (const v2f*)(w2 + j * NF);   // uniform -> s_load
        v2f vv = {v, v};
        #pragma unroll
        for (int i = 0; i < 16; i++) o[i] = PKFMA(vv, w2r[i], o[i]);
    }
    #pragma unroll
    for (int f = 0; f < NF; f++) {                // residual read-modify-write
        float* addr = hp + (size_t)f * AW + e;
        *addr = (*addr + o[f >> 1][f & 1]) * mk;
    }
}

// ---------------------------------------------------------------- RMS over (a,w)
__global__ __launch_bounds__(256) void rms_kernel(
    const float* __restrict__ h, const int* __restrict__ rows_len,
    const int* __restrict__ cols_len, float* __restrict__ rms)
{
    int bc = blockIdx.x;
    int f = threadIdx.x >> 3, g = threadIdx.x & 7;
    const float* p = h + ((size_t)bc * NF + f) * AW;
    float s = 0.f;
    for (int i = g; i < AW; i += 8) { float v = p[i]; s = fmaf(v, v, s); }
    __shared__ float red[NF][9];
    red[f][g] = s;
    __syncthreads();
    if (threadIdx.x < NF) {
        float t = 0.f;
        #pragma unroll
        for (int g2 = 0; g2 < 8; g2++) t += red[threadIdx.x][g2];
        float n = (float)(rows_len[bc] * cols_len[bc]);
        t = fmaxf(t, 1e-20f);
        rms[bc * NF + threadIdx.x] = sqrtf(t / fmaxf(n, 1e-12f));
    }
}

// ---------------------------------------------------------------- final mean-over-C + MLP + tanh
__global__ __launch_bounds__(64) void out_kernel(
    const float* __restrict__ rms, const float* __restrict__ w1,
    const float* __restrict__ b1, const float* __restrict__ w2,
    const float* __restrict__ b2, float* __restrict__ out)
{
    int b = threadIdx.x;
    if (b >= NB) return;
    float hm[NF];
    #pragma unroll
    for (int f = 0; f < NF; f++) {
        float s = 0.f;
        for (int c = 0; c < NC; c++) s += rms[(b * NC + c) * NF + f];
        hm[f] = s / (float)NC;
    }
    float o0 = b2[0], o1 = b2[1];
    for (int j = 0; j < NHID; j++) {
        float v = b1[j];
        #pragma unroll
        for (int f = 0; f < NF; f++) v = fmaf(hm[f], w1[f * NHID + j], v);
        v = fmaxf(v, 0.f);
        o0 = fmaf(v, w2[j * 2 + 0], o0);
        o1 = fmaf(v, w2[j * 2 + 1], o1);
    }
    out[b * 2 + 0] = 8.f * tanhf(o0);
    out[b * 2 + 1] = 8.f * tanhf(o1);
}

// ---------------------------------------------------------------- launcher
extern "C" void kernel_launch(void* const* d_in, const int* in_sizes, int n_in,
                              void* d_out, int out_size, void* d_ws, size_t ws_size,
                              hipStream_t stream)
{
    const float* x    = (const float*)d_in[0];
    const int* rl     = (const int*)d_in[1];
    const int* cl     = (const int*)d_in[2];
    const float* t0w1 = (const float*)d_in[3];
    const float* t0b1 = (const float*)d_in[4];
    const float* t0w2 = (const float*)d_in[5];
    const float* t0b2 = (const float*)d_in[6];
    const float* tw1  = (const float*)d_in[7];
    const float* tb1  = (const float*)d_in[8];
    const float* tw2  = (const float*)d_in[9];
    const float* tb2  = (const float*)d_in[10];
    const float* ow1  = (const float*)d_in[11];
    const float* ob1  = (const float*)d_in[12];
    const float* ow2  = (const float*)d_in[13];
    const float* ob2  = (const float*)d_in[14];
    float* out = (float*)d_out;

    float* ws    = (float*)d_ws;
    float* h     = ws;                               // NEL*NF  (planar [bc][f][a*96+w])
    float* stats = h + NEL * NF;                     // 2*NBC
    float* rowb  = stats + 2 * NBC;                  // NBC*NA*8
    float* colb  = rowb + (size_t)NBC * NA * 8;      // NBC*NW*8
    float* matb  = colb + (size_t)NBC * NW * 8;      // NBC*8
    float* cmxb  = matb + NBC * 8;                   // NBC*NF
    float* rmsb  = cmxb + NBC * NF;                  // NBC*NF
    float* w1tb  = rmsb + NBC * NF;                  // 4*NHID*24
    float* rowcb = w1tb + 4 * NHID * 24;             // NBC*NHID*NA
    float* colcb = rowcb + (size_t)NBC * NHID * NA;  // NBC*NHID*NW

    stats_kernel<<<NBC, 256, 0, stream>>>(x, rl, cl, stats);
    prep_kernel<<<(4 * NHID * 24 + 255) / 256, 256, 0, stream>>>(tw1, w1tb);
    t0_kernel<<<(int)(NEL / 512), 256, 0, stream>>>(x, rl, cl, stats,
                                                    t0w1, t0b1, t0w2, t0b2, h);
    for (int s = 0; s < 4; s++) {
        pool_kernel<<<NBC * NF, 256, 0, stream>>>(h, rowb, colb, matb, cmxb);
        precomp_kernel<<<NBC, 256, 0, stream>>>(rowb, colb, matb, cmxb,
            tw1 + (size_t)s * 64 * NHID, tb1 + s * NHID, rowcb, colcb);
        mlp_kernel<<<NBC * 18, 512, 0, stream>>>(h, rowcb, colcb, rl, cl,
            w1tb + (size_t)s * NHID * 24,
            tw2 + (size_t)s * NHID * NF, tb2 + s * NF);
    }
    rms_kernel<<<NBC, 256, 0, stream>>>(h, rl, cl, rmsb);
    out_kernel<<<1, 64, 0, stream>>>(rmsb, ow1, ob1, ow2, ob2, out);
}